// Round 1
// baseline (23081.520 us; speedup 1.0000x reference)
//
#include <hip/hip_runtime.h>
#include <hip/hip_bf16.h>

#define NB 64
#define TT 1024
#define ND 512
#define NH 1024
#define GRID 256
#define NTH 256

typedef float f32x4 __attribute__((ext_vector_type(4)));
typedef __bf16 bf16x8 __attribute__((ext_vector_type(8)));

__device__ __forceinline__ float sigmoid_f(float v) { return 1.0f / (1.0f + __expf(-v)); }

__device__ __forceinline__ float tanh_f(float v) {
    float a = fabsf(v);
    float e = __expf(-2.0f * a);
    float t = (1.0f - e) / (1.0f + e);
    return copysignf(t, v);
}

// Swizzled LDS weight read: row-major [rows][K] bf16, byte ^= (row&7)<<4
// breaks the same-bank column pattern (stride 1024/2048 B) into 2-way (free).
__device__ __forceinline__ bf16x8 ld_w(const __bf16* base, int row, int k0, int K) {
    unsigned off = ((unsigned)(row * K + k0) << 1) ^ (((unsigned)row & 7u) << 4);
    return *(const bf16x8*)((const char*)base + off);
}

__global__ void __launch_bounds__(NTH) gru_kernel(
    const float* __restrict__ x, const float* __restrict__ W_ih,
    const float* __restrict__ W_hh, const float* __restrict__ b_ih,
    const float* __restrict__ b_hh, float* __restrict__ out,
    unsigned* __restrict__ bar, __bf16* __restrict__ hbuf)
{
    extern __shared__ char smem[];
    __bf16* Wih_s = (__bf16*)smem;            // [48][512] bf16, swizzled
    __bf16* Whh_s = Wih_s + 48 * ND;          // [48][1024] bf16, swizzled
    float* prz = (float*)(Whh_s + 48 * NH);   // [4 waves][16 m][32] (r|z) partial sums (x+h combined)
    float* pnx = prz + 4 * 16 * 32;           // [4][16][16] n-gate x-part
    float* pnh = pnx + 4 * 16 * 16;           // [4][16][16] n-gate h-part
    // total = 49152 + 98304 + 8192 + 4096 + 4096 = 163840 B

    const int tid = threadIdx.x;
    const int bg = blockIdx.x >> 6;   // batch group (16 rows)
    const int cg = blockIdx.x & 63;   // hidden-col group (16 cols)
    const int brow = bg << 4;
    const int hc0 = cg << 4;

    // ---- one-time: load weight slices fp32->bf16 into LDS (swizzled) ----
    for (int i = tid; i < 48 * 128; i += NTH) {          // W_ih: 48 rows x 128 float4
        int rr = i >> 7;
        int c = (i & 127) << 2;
        int grow = (rr >> 4) * NH + hc0 + (rr & 15);     // gate*1024 + col
        float4 v = *(const float4*)(W_ih + (size_t)grow * ND + c);
        unsigned off = ((unsigned)(rr * ND + c) << 1) ^ (((unsigned)rr & 7u) << 4);
        __bf16* d = (__bf16*)((char*)Wih_s + off);
        d[0] = (__bf16)v.x; d[1] = (__bf16)v.y; d[2] = (__bf16)v.z; d[3] = (__bf16)v.w;
    }
    for (int i = tid; i < 48 * 256; i += NTH) {          // W_hh: 48 rows x 256 float4
        int rr = i >> 8;
        int c = (i & 255) << 2;
        int grow = (rr >> 4) * NH + hc0 + (rr & 15);
        float4 v = *(const float4*)(W_hh + (size_t)grow * NH + c);
        unsigned off = ((unsigned)(rr * NH + c) << 1) ^ (((unsigned)rr & 7u) << 4);
        __bf16* d = (__bf16*)((char*)Whh_s + off);
        d[0] = (__bf16)v.x; d[1] = (__bf16)v.y; d[2] = (__bf16)v.z; d[3] = (__bf16)v.w;
    }

    // per-thread bias registers for gate-math role (thread -> (mrow, jcol))
    const int jcol = tid & 15;
    const int mrow = tid >> 4;
    const float b_r = b_ih[hc0 + jcol] + b_hh[hc0 + jcol];
    const float b_z = b_ih[NH + hc0 + jcol] + b_hh[NH + hc0 + jcol];
    const float b_nx = b_ih[2 * NH + hc0 + jcol];
    const float b_nh = b_hh[2 * NH + hc0 + jcol];

    __syncthreads();

    const int wave = tid >> 6;
    const int lane = tid & 63;
    const int lrow = lane & 15;     // A-frag row (batch) / B-frag col (gate col)
    const int kgrp = lane >> 4;     // k offset group (*8)

    // uniform K split: each wave does x-K [wave*128,+128) and h-K [wave*256,+256)
    const int xk_base = wave * 128 + kgrp * 8;
    const int hk_base = wave * 256 + kgrp * 8;

    int p = 0;
    for (int t = 0; t < TT; ++t) {
        f32x4 ar{}, az{}, anx{}, anh{};

        // x-part (fp32 -> bf16 on the fly)
        const float* xrow = x + ((size_t)(brow + lrow) * TT + t) * ND;
        #pragma unroll
        for (int it = 0; it < 4; ++it) {
            int k0 = xk_base + it * 32;
            float4 va = *(const float4*)(xrow + k0);
            float4 vb = *(const float4*)(xrow + k0 + 4);
            bf16x8 af;
            af[0] = (__bf16)va.x; af[1] = (__bf16)va.y; af[2] = (__bf16)va.z; af[3] = (__bf16)va.w;
            af[4] = (__bf16)vb.x; af[5] = (__bf16)vb.y; af[6] = (__bf16)vb.z; af[7] = (__bf16)vb.w;
            bf16x8 wr = ld_w(Wih_s, lrow, k0, ND);
            bf16x8 wz = ld_w(Wih_s, 16 + lrow, k0, ND);
            bf16x8 wn = ld_w(Wih_s, 32 + lrow, k0, ND);
            ar  = __builtin_amdgcn_mfma_f32_16x16x32_bf16(af, wr, ar, 0, 0, 0);
            az  = __builtin_amdgcn_mfma_f32_16x16x32_bf16(af, wz, az, 0, 0, 0);
            anx = __builtin_amdgcn_mfma_f32_16x16x32_bf16(af, wn, anx, 0, 0, 0);
        }
        // h-part (bf16 state buffer)
        const __bf16* hrow = hbuf + (size_t)p * NB * NH + (size_t)(brow + lrow) * NH;
        #pragma unroll
        for (int it = 0; it < 8; ++it) {
            int k0 = hk_base + it * 32;
            bf16x8 af = *(const bf16x8*)(hrow + k0);
            bf16x8 wr = ld_w(Whh_s, lrow, k0, NH);
            bf16x8 wz = ld_w(Whh_s, 16 + lrow, k0, NH);
            bf16x8 wn = ld_w(Whh_s, 32 + lrow, k0, NH);
            ar  = __builtin_amdgcn_mfma_f32_16x16x32_bf16(af, wr, ar, 0, 0, 0);
            az  = __builtin_amdgcn_mfma_f32_16x16x32_bf16(af, wz, az, 0, 0, 0);
            anh = __builtin_amdgcn_mfma_f32_16x16x32_bf16(af, wn, anh, 0, 0, 0);
        }
        // D layout: col = lane&15, row = (lane>>4)*4 + j  (m89-verified)
        #pragma unroll
        for (int j = 0; j < 4; ++j) {
            int row = kgrp * 4 + j;
            prz[wave * 512 + row * 32 + lrow]      = ar[j];
            prz[wave * 512 + row * 32 + 16 + lrow] = az[j];
            pnx[wave * 256 + row * 16 + lrow]      = anx[j];
            pnh[wave * 256 + row * 16 + lrow]      = anh[j];
        }
        __syncthreads();

        // ---- gate math: one thread per (mrow, jcol) output element ----
        {
            float rpre = prz[mrow * 32 + jcol] + prz[512 + mrow * 32 + jcol]
                       + prz[1024 + mrow * 32 + jcol] + prz[1536 + mrow * 32 + jcol] + b_r;
            float zpre = prz[mrow * 32 + 16 + jcol] + prz[512 + mrow * 32 + 16 + jcol]
                       + prz[1024 + mrow * 32 + 16 + jcol] + prz[1536 + mrow * 32 + 16 + jcol] + b_z;
            float ginn = pnx[mrow * 16 + jcol] + pnx[256 + mrow * 16 + jcol]
                       + pnx[512 + mrow * 16 + jcol] + pnx[768 + mrow * 16 + jcol] + b_nx;
            float ghnn = pnh[mrow * 16 + jcol] + pnh[256 + mrow * 16 + jcol]
                       + pnh[512 + mrow * 16 + jcol] + pnh[768 + mrow * 16 + jcol] + b_nh;
            float r = sigmoid_f(rpre);
            float z = sigmoid_f(zpre);
            float n = tanh_f(ginn + r * ghnn);
            size_t orow = ((size_t)(brow + mrow) * TT + t) * NH + hc0 + jcol;
            float hp = (t > 0) ? out[orow - NH] : 0.0f;   // fp32 carry from own prior res write
            float hn = (1.0f - z) * n + z * hp;
            out[orow] = hn;
            hbuf[(size_t)(p ^ 1) * NB * NH + (size_t)(brow + mrow) * NH + hc0 + jcol] = (__bf16)hn;
            if (t == TT - 1)
                out[(size_t)NB * TT * NH + (size_t)(brow + mrow) * NH + hc0 + jcol] = hn;
        }

        p ^= 1;
        // ---- grid barrier (monotonic counter; all 256 blocks co-resident) ----
        if (t < TT - 1) {
            __syncthreads();
            if (tid == 0) {
                __threadfence();  // release: flush h writes to device scope
                __hip_atomic_fetch_add(bar, 1u, __ATOMIC_RELAXED, __HIP_MEMORY_SCOPE_AGENT);
                const unsigned tgt = (unsigned)GRID * (unsigned)(t + 1);
                while (__hip_atomic_load(bar, __ATOMIC_RELAXED, __HIP_MEMORY_SCOPE_AGENT) < tgt) {
                    __builtin_amdgcn_s_sleep(1);
                }
                __threadfence();  // acquire: invalidate stale cached h
            }
            __syncthreads();
        }
    }
}

extern "C" void kernel_launch(void* const* d_in, const int* in_sizes, int n_in,
                              void* d_out, int out_size, void* d_ws, size_t ws_size,
                              hipStream_t stream) {
    (void)in_sizes; (void)n_in; (void)out_size;
    const float* x    = (const float*)d_in[0];
    const float* W_ih = (const float*)d_in[1];
    const float* W_hh = (const float*)d_in[2];
    const float* b_ih = (const float*)d_in[3];
    const float* b_hh = (const float*)d_in[4];
    float* out = (float*)d_out;

    // ws layout: [0,256) barrier counter; [256, 256 + 2*64*1024*2) bf16 h double buffer
    unsigned* bar = (unsigned*)d_ws;
    __bf16* hbuf = (__bf16*)((char*)d_ws + 256);
    const size_t clear_bytes = 256 + (size_t)2 * NB * NH * sizeof(__bf16);
    if (ws_size < clear_bytes) return;
    hipMemsetAsync(d_ws, 0, clear_bytes, stream);  // zero h0 + reset barrier (replay-safe)

    const size_t smem_bytes = (size_t)48 * ND * 2 + (size_t)48 * NH * 2
                            + (4 * 16 * 32 + 4 * 16 * 16 + 4 * 16 * 16) * sizeof(float); // 163840
    // opt-in for >64KB dynamic LDS (no-op if unnecessary on ROCm)
    (void)hipFuncSetAttribute((const void*)gru_kernel,
                              hipFuncAttributeMaxDynamicSharedMemorySize, (int)smem_bytes);
    gru_kernel<<<GRID, NTH, smem_bytes, stream>>>(x, W_ih, W_hh, b_ih, b_hh, out, bar, hbuf);
}